// Round 1
// baseline (1866.192 us; speedup 1.0000x reference)
//
#include <hip/hip_runtime.h>
#include <cstdio>

#define NU 250000
#define NI 250000
#define NE 500000

// ---------------- degree ----------------
__global__ void deg_kernel(const int* __restrict__ dst, float* __restrict__ deg, int n) {
  int i = blockIdx.x * blockDim.x + threadIdx.x;
  if (i < n) unsafeAtomicAdd(&deg[dst[i]], 1.0f);
}

__global__ void rdeg_kernel(float* __restrict__ deg, int n) {
  int i = blockIdx.x * blockDim.x + threadIdx.x;
  if (i < n) { float d = deg[i]; deg[i] = 1.0f / fmaxf(d, 1.0f); }
}

// ---------------- layer-1 GEMM: [n,128] @ [128,64] + b, 1 or 2 etypes fused ----------------
template <bool TWO>
__global__ __launch_bounds__(256) void gemm_kernel(
    const float* __restrict__ X, int n,
    const float* __restrict__ Wa, const float* __restrict__ ba,
    const float* __restrict__ Wb, const float* __restrict__ bb,
    float* __restrict__ Ya, float* __restrict__ Yb) {
  __shared__ float sf[64 * 132];  // 64 nodes x 128 feats, row stride 132 (pad, 16B-aligned rows)
  const int n0 = blockIdx.x * 64;
  const int tid = threadIdx.x;

  // stage 64x128 floats (float4 loads, coalesced)
  #pragma unroll
  for (int it = 0; it < 8; ++it) {
    int idx = tid + it * 256;      // 0..2047 float4 slots
    int row = idx >> 5;
    int c4 = idx & 31;
    float4 v = make_float4(0.f, 0.f, 0.f, 0.f);
    int node = n0 + row;
    if (node < n) v = *(const float4*)&X[(size_t)node * 128 + c4 * 4];
    *(float4*)&sf[row * 132 + c4 * 4] = v;
  }
  __syncthreads();

  const int jg = (tid & 15) * 4;   // output col group
  const int ng = (tid >> 4) * 4;   // node group
  float accA[4][4] = {};
  float accB[4][4] = {};

  for (int k = 0; k < 128; k += 4) {
    float fr[4][4];
    #pragma unroll
    for (int i = 0; i < 4; ++i) {
      float4 t = *(const float4*)&sf[(ng + i) * 132 + k];
      fr[i][0] = t.x; fr[i][1] = t.y; fr[i][2] = t.z; fr[i][3] = t.w;
    }
    #pragma unroll
    for (int kk = 0; kk < 4; ++kk) {
      float4 wa = *(const float4*)&Wa[(k + kk) * 64 + jg];
      float4 wb = make_float4(0.f, 0.f, 0.f, 0.f);
      if constexpr (TWO) wb = *(const float4*)&Wb[(k + kk) * 64 + jg];
      #pragma unroll
      for (int i = 0; i < 4; ++i) {
        float fv = fr[i][kk];
        accA[i][0] += fv * wa.x; accA[i][1] += fv * wa.y;
        accA[i][2] += fv * wa.z; accA[i][3] += fv * wa.w;
        if constexpr (TWO) {
          accB[i][0] += fv * wb.x; accB[i][1] += fv * wb.y;
          accB[i][2] += fv * wb.z; accB[i][3] += fv * wb.w;
        }
      }
    }
  }

  float4 bav = *(const float4*)&ba[jg];
  float4 bbv = make_float4(0.f, 0.f, 0.f, 0.f);
  if constexpr (TWO) bbv = *(const float4*)&bb[jg];
  #pragma unroll
  for (int i = 0; i < 4; ++i) {
    int node = n0 + ng + i;
    if (node < n) {
      float4 oa;
      oa.x = accA[i][0] + bav.x; oa.y = accA[i][1] + bav.y;
      oa.z = accA[i][2] + bav.z; oa.w = accA[i][3] + bav.w;
      *(float4*)&Ya[(size_t)node * 64 + jg] = oa;
      if constexpr (TWO) {
        float4 ob;
        ob.x = accB[i][0] + bbv.x; ob.y = accB[i][1] + bbv.y;
        ob.z = accB[i][2] + bbv.z; ob.w = accB[i][3] + bbv.w;
        *(float4*)&Yb[(size_t)node * 64 + jg] = ob;
      }
    }
  }
}

// ---------------- layer-1 scatter: out[dst] += Wh[src] * rdeg[dst], 16 lanes/edge ----------------
__global__ void scatter1_kernel(const float* __restrict__ Wh,
                                const int* __restrict__ src, const int* __restrict__ dst,
                                const float* __restrict__ rdeg,
                                float* __restrict__ out, int n_edges) {
  int t = blockIdx.x * blockDim.x + threadIdx.x;
  int e = t >> 4, q = t & 15;
  if (e >= n_edges) return;
  int s = src[e], d = dst[e];
  float r = rdeg[d];
  float4 v = *(const float4*)&Wh[(size_t)s * 64 + q * 4];
  float* o = &out[(size_t)d * 64 + q * 4];
  unsafeAtomicAdd(o + 0, v.x * r);
  unsafeAtomicAdd(o + 1, v.y * r);
  unsafeAtomicAdd(o + 2, v.z * r);
  unsafeAtomicAdd(o + 3, v.w * r);
}

// ---------------- leaky relu in place ----------------
__global__ void leaky_kernel(float* __restrict__ p, long n4) {
  long i = blockIdx.x * (long)blockDim.x + threadIdx.x;
  long stride = gridDim.x * (long)blockDim.x;
  for (; i < n4; i += stride) {
    float4 v = ((float4*)p)[i];
    v.x = v.x >= 0.f ? v.x : 0.01f * v.x;
    v.y = v.y >= 0.f ? v.y : 0.01f * v.y;
    v.z = v.z >= 0.f ? v.z : 0.01f * v.z;
    v.w = v.w >= 0.f ? v.w : 0.01f * v.w;
    ((float4*)p)[i] = v;
  }
}

// ---------------- layer-2 scatter: out[dst] += (H[src]@W2 + b2) * rdeg[dst], 16 lanes/edge ----------------
__global__ void scatter2_kernel(const float* __restrict__ H,
                                const int* __restrict__ src, const int* __restrict__ dst,
                                const float* __restrict__ rdeg,
                                const float* __restrict__ W2, const float* __restrict__ b2,
                                float* __restrict__ out, int n_edges) {
  int t = blockIdx.x * blockDim.x + threadIdx.x;
  int e = t >> 4, q = t & 15;
  if (e >= n_edges) return;
  int s = src[e], d = dst[e];
  float r = rdeg[d];
  float4 h = *(const float4*)&H[(size_t)s * 64 + q * 4];
  const float2* W2v = (const float2*)W2;  // [64] rows of (c0,c1)
  float2 w0 = W2v[q * 4 + 0], w1 = W2v[q * 4 + 1];
  float2 w2 = W2v[q * 4 + 2], w3 = W2v[q * 4 + 3];
  float s0 = h.x * w0.x + h.y * w1.x + h.z * w2.x + h.w * w3.x;
  float s1 = h.x * w0.y + h.y * w1.y + h.z * w2.y + h.w * w3.y;
  #pragma unroll
  for (int off = 1; off < 16; off <<= 1) {
    s0 += __shfl_xor(s0, off, 64);
    s1 += __shfl_xor(s1, off, 64);
  }
  if (q == 0) {
    float* o = &out[(size_t)d * 2];
    unsafeAtomicAdd(o + 0, (s0 + b2[0]) * r);
    unsafeAtomicAdd(o + 1, (s1 + b2[1]) * r);
  }
}

extern "C" void kernel_launch(void* const* d_in, const int* in_sizes, int n_in,
                              void* d_out, int out_size, void* d_ws, size_t ws_size,
                              hipStream_t stream) {
  const float* feat_user = (const float*)d_in[0];
  const float* feat_item = (const float*)d_in[1];
  const float* W1f = (const float*)d_in[2];  const float* b1f = (const float*)d_in[3];
  const float* W1c = (const float*)d_in[4];  const float* b1c = (const float*)d_in[5];
  const float* W1r = (const float*)d_in[6];  const float* b1r = (const float*)d_in[7];
  const float* W2f = (const float*)d_in[8];  const float* b2f = (const float*)d_in[9];
  const float* W2c = (const float*)d_in[10]; const float* b2c = (const float*)d_in[11];
  const float* W2r = (const float*)d_in[12]; const float* b2r = (const float*)d_in[13];
  const int* fsrc = (const int*)d_in[14];  const int* fdst = (const int*)d_in[15];
  const int* csrc = (const int*)d_in[16];  const int* cdst = (const int*)d_in[17];
  const int* rsrc = (const int*)d_in[18];  const int* rdst = (const int*)d_in[19];

  float* out = (float*)d_out;
  float* out_u = out;                 // [NU*2]
  float* out_i = out + 2 * NU;        // [NI*2]
  float* h2u  = out + 1000000;        // [NU*64]
  float* h2i  = out + 17000000;       // [NI*64]

  float* ws = (float*)d_ws;
  float* Whf = ws;                    // 16M floats
  float* Whc = ws + 16000000;
  float* Whr = ws + 32000000;
  float* degf = ws + 48000000;        // 250K
  float* degc = degf + NU;
  float* degr = degc + NI;
  size_t need = (48000000ull + 750000ull) * 4ull;
  if (ws_size < need) {
    fprintf(stderr, "kernel_launch: ws too small (%zu < %zu)\n", ws_size, need);
    return;
  }

  hipMemsetAsync(d_out, 0, (size_t)out_size * 4, stream);
  hipMemsetAsync(degf, 0, 750000ull * 4ull, stream);

  // degrees -> reciprocals
  int db = (NE + 255) / 256;
  deg_kernel<<<db, 256, 0, stream>>>(fdst, degf, NE);
  deg_kernel<<<db, 256, 0, stream>>>(cdst, degc, NE);
  deg_kernel<<<db, 256, 0, stream>>>(rdst, degr, NE);
  rdeg_kernel<<<(750000 + 255) / 256, 256, 0, stream>>>(degf, 750000);

  // layer-1 GEMMs (user fused for follows+clicks)
  gemm_kernel<true><<<(NU + 63) / 64, 256, 0, stream>>>(feat_user, NU, W1f, b1f, W1c, b1c, Whf, Whc);
  gemm_kernel<false><<<(NI + 63) / 64, 256, 0, stream>>>(feat_item, NI, W1r, b1r, nullptr, nullptr, Whr, nullptr);

  // layer-1 aggregation (means accumulate into h2 regions of d_out)
  int sb = (NE * 16 + 255) / 256;  // 31250
  scatter1_kernel<<<sb, 256, 0, stream>>>(Whf, fsrc, fdst, degf, h2u, NE);
  scatter1_kernel<<<sb, 256, 0, stream>>>(Whr, rsrc, rdst, degr, h2u, NE);
  scatter1_kernel<<<sb, 256, 0, stream>>>(Whc, csrc, cdst, degc, h2i, NE);

  // leaky relu in place over h2u..h2i (contiguous 32M floats)
  leaky_kernel<<<2048, 256, 0, stream>>>(h2u, 8000000L);

  // layer-2: per-edge 64->2 dot + scatter
  scatter2_kernel<<<sb, 256, 0, stream>>>(h2u, fsrc, fdst, degf, W2f, b2f, out_u, NE);
  scatter2_kernel<<<sb, 256, 0, stream>>>(h2i, rsrc, rdst, degr, W2r, b2r, out_u, NE);
  scatter2_kernel<<<sb, 256, 0, stream>>>(h2u, csrc, cdst, degc, W2c, b2c, out_i, NE);
}

// Round 2
// 551.210 us; speedup vs baseline: 3.3856x; 3.3856x over previous
//
#include <hip/hip_runtime.h>
#include <cstdio>

#define NU 250000
#define NI 250000
#define NE 500000
#define ND 250000            // all three dst domains are 250K
#define NB_SCAN 245          // ceil(ND / 1024)

// ---- bf16 helpers (bit-level, round-to-nearest-even) ----
__device__ inline unsigned short f2bf(float x) {
  unsigned int b = __float_as_uint(x);
  unsigned int r = (b + 0x7FFFu + ((b >> 16) & 1u)) >> 16;
  return (unsigned short)r;
}
__device__ inline float bf2f(unsigned short u) {
  return __uint_as_float(((unsigned int)u) << 16);
}

// ---------------- CSR build: histogram -> scan -> bucket fill ----------------
__global__ void hist_kernel(const int* __restrict__ dst, int* __restrict__ deg) {
  int i = blockIdx.x * blockDim.x + threadIdx.x;
  if (i < NE) atomicAdd(&deg[dst[i]], 1);
}

__global__ void scan1_kernel(const int* __restrict__ deg, int* __restrict__ bsum) {
  __shared__ int s[256];
  int b = blockIdx.x, t = threadIdx.x;
  int base = b * 1024 + t * 4;
  int v = 0;
  #pragma unroll
  for (int i = 0; i < 4; ++i) if (base + i < ND) v += deg[base + i];
  s[t] = v; __syncthreads();
  for (int off = 128; off > 0; off >>= 1) { if (t < off) s[t] += s[t + off]; __syncthreads(); }
  if (t == 0) bsum[b] = s[0];
}

__global__ void scan2_kernel(int* __restrict__ bsum) {
  __shared__ int s[256];
  int t = threadIdx.x;
  s[t] = (t < NB_SCAN) ? bsum[t] : 0;
  __syncthreads();
  for (int off = 1; off < 256; off <<= 1) {
    int x = (t >= off) ? s[t - off] : 0;
    __syncthreads();
    s[t] += x;
    __syncthreads();
  }
  if (t < NB_SCAN) bsum[t] = (t == 0) ? 0 : s[t - 1];
}

__global__ void scan3_kernel(const int* __restrict__ deg, const int* __restrict__ bsum,
                             int* __restrict__ offs, int* __restrict__ cursor) {
  __shared__ int s[256];
  int b = blockIdx.x, t = threadIdx.x;
  int base = b * 1024 + t * 4;
  int v[4]; int sum = 0;
  #pragma unroll
  for (int i = 0; i < 4; ++i) { v[i] = (base + i < ND) ? deg[base + i] : 0; sum += v[i]; }
  s[t] = sum; __syncthreads();
  for (int off = 1; off < 256; off <<= 1) {
    int x = (t >= off) ? s[t - off] : 0;
    __syncthreads();
    s[t] += x;
    __syncthreads();
  }
  int run = bsum[b] + s[t] - sum;   // exclusive prefix for this thread's chunk
  #pragma unroll
  for (int i = 0; i < 4; ++i) {
    if (base + i < ND) { offs[base + i] = run; cursor[base + i] = run; run += v[i]; }
  }
  if (b == 0 && t == 0) offs[ND] = NE;
}

__global__ void bucket_kernel(const int* __restrict__ src, const int* __restrict__ dst,
                              int* __restrict__ cursor, int* __restrict__ sorted) {
  int e = blockIdx.x * blockDim.x + threadIdx.x;
  if (e < NE) {
    int pos = atomicAdd(&cursor[dst[e]], 1);
    sorted[pos] = src[e];
  }
}

// ---------------- layer-1 GEMM: [n,128] @ [128,64] + b -> bf16, 1 or 2 etypes fused ----------------
template <bool TWO>
__global__ __launch_bounds__(256) void gemm_kernel(
    const float* __restrict__ X, int n,
    const float* __restrict__ Wa, const float* __restrict__ ba,
    const float* __restrict__ Wb, const float* __restrict__ bb,
    unsigned short* __restrict__ Ya, unsigned short* __restrict__ Yb) {
  __shared__ float sf[64 * 132];
  const int n0 = blockIdx.x * 64;
  const int tid = threadIdx.x;

  #pragma unroll
  for (int it = 0; it < 8; ++it) {
    int idx = tid + it * 256;
    int row = idx >> 5;
    int c4 = idx & 31;
    float4 v = make_float4(0.f, 0.f, 0.f, 0.f);
    int node = n0 + row;
    if (node < n) v = *(const float4*)&X[(size_t)node * 128 + c4 * 4];
    *(float4*)&sf[row * 132 + c4 * 4] = v;
  }
  __syncthreads();

  const int jg = (tid & 15) * 4;
  const int ng = (tid >> 4) * 4;
  float accA[4][4] = {};
  float accB[4][4] = {};

  for (int k = 0; k < 128; k += 4) {
    float fr[4][4];
    #pragma unroll
    for (int i = 0; i < 4; ++i) {
      float4 t = *(const float4*)&sf[(ng + i) * 132 + k];
      fr[i][0] = t.x; fr[i][1] = t.y; fr[i][2] = t.z; fr[i][3] = t.w;
    }
    #pragma unroll
    for (int kk = 0; kk < 4; ++kk) {
      float4 wa = *(const float4*)&Wa[(k + kk) * 64 + jg];
      float4 wb = make_float4(0.f, 0.f, 0.f, 0.f);
      if constexpr (TWO) wb = *(const float4*)&Wb[(k + kk) * 64 + jg];
      #pragma unroll
      for (int i = 0; i < 4; ++i) {
        float fv = fr[i][kk];
        accA[i][0] += fv * wa.x; accA[i][1] += fv * wa.y;
        accA[i][2] += fv * wa.z; accA[i][3] += fv * wa.w;
        if constexpr (TWO) {
          accB[i][0] += fv * wb.x; accB[i][1] += fv * wb.y;
          accB[i][2] += fv * wb.z; accB[i][3] += fv * wb.w;
        }
      }
    }
  }

  float4 bav = *(const float4*)&ba[jg];
  float4 bbv = make_float4(0.f, 0.f, 0.f, 0.f);
  if constexpr (TWO) bbv = *(const float4*)&bb[jg];
  #pragma unroll
  for (int i = 0; i < 4; ++i) {
    int node = n0 + ng + i;
    if (node < n) {
      ushort4 oa;
      oa.x = f2bf(accA[i][0] + bav.x); oa.y = f2bf(accA[i][1] + bav.y);
      oa.z = f2bf(accA[i][2] + bav.z); oa.w = f2bf(accA[i][3] + bav.w);
      *(ushort4*)&Ya[(size_t)node * 64 + jg] = oa;
      if constexpr (TWO) {
        ushort4 ob;
        ob.x = f2bf(accB[i][0] + bbv.x); ob.y = f2bf(accB[i][1] + bbv.y);
        ob.z = f2bf(accB[i][2] + bbv.z); ob.w = f2bf(accB[i][3] + bbv.w);
        *(ushort4*)&Yb[(size_t)node * 64 + jg] = ob;
      }
    }
  }
}

// ---------------- layer-1 gather-aggregate for users (follows + rev), fused leaky + layer-2 GEMM ----------------
__global__ __launch_bounds__(256) void agg_user_kernel(
    const unsigned short* __restrict__ Whf, const unsigned short* __restrict__ Whr,
    const int* __restrict__ offs_f, const int* __restrict__ srt_f,
    const int* __restrict__ offs_r, const int* __restrict__ srt_r,
    const float* __restrict__ W2f, const float* __restrict__ b2f,
    const float* __restrict__ W2c, const float* __restrict__ b2c,
    float* __restrict__ h2u, float* __restrict__ Y2f, float* __restrict__ Y2c) {
  int t = blockIdx.x * 256 + threadIdx.x;
  int d = t >> 4, q = t & 15;
  if (d >= NU) return;

  float af[4] = {0.f, 0.f, 0.f, 0.f};
  int f0 = offs_f[d], f1 = offs_f[d + 1];
  for (int e = f0; e < f1; ++e) {
    int s = srt_f[e];
    ushort4 v = *(const ushort4*)&Whf[(size_t)s * 64 + q * 4];
    af[0] += bf2f(v.x); af[1] += bf2f(v.y); af[2] += bf2f(v.z); af[3] += bf2f(v.w);
  }
  float rf = 1.0f / fmaxf((float)(f1 - f0), 1.0f);

  float ar[4] = {0.f, 0.f, 0.f, 0.f};
  int r0 = offs_r[d], r1 = offs_r[d + 1];
  for (int e = r0; e < r1; ++e) {
    int s = srt_r[e];
    ushort4 v = *(const ushort4*)&Whr[(size_t)s * 64 + q * 4];
    ar[0] += bf2f(v.x); ar[1] += bf2f(v.y); ar[2] += bf2f(v.z); ar[3] += bf2f(v.w);
  }
  float rr = 1.0f / fmaxf((float)(r1 - r0), 1.0f);

  float h[4];
  #pragma unroll
  for (int i = 0; i < 4; ++i) {
    float x = af[i] * rf + ar[i] * rr;
    h[i] = x >= 0.f ? x : 0.01f * x;
  }
  *(float4*)&h2u[(size_t)d * 64 + q * 4] = make_float4(h[0], h[1], h[2], h[3]);

  // fused layer-2: y = h @ W2 + b2 for follows (user->user) and clicks (user->item)
  float pf0 = 0.f, pf1 = 0.f, pc0 = 0.f, pc1 = 0.f;
  #pragma unroll
  for (int i = 0; i < 4; ++i) {
    int j = q * 4 + i;
    pf0 += h[i] * W2f[j * 2 + 0]; pf1 += h[i] * W2f[j * 2 + 1];
    pc0 += h[i] * W2c[j * 2 + 0]; pc1 += h[i] * W2c[j * 2 + 1];
  }
  #pragma unroll
  for (int off = 1; off < 16; off <<= 1) {
    pf0 += __shfl_xor(pf0, off, 64);
    pf1 += __shfl_xor(pf1, off, 64);
    pc0 += __shfl_xor(pc0, off, 64);
    pc1 += __shfl_xor(pc1, off, 64);
  }
  if (q == 0) {
    Y2f[(size_t)d * 2 + 0] = pf0 + b2f[0];
    Y2f[(size_t)d * 2 + 1] = pf1 + b2f[1];
    Y2c[(size_t)d * 2 + 0] = pc0 + b2c[0];
    Y2c[(size_t)d * 2 + 1] = pc1 + b2c[1];
  }
}

// ---------------- layer-1 gather-aggregate for items (clicks), fused leaky + layer-2 GEMM (rev) ----------------
__global__ __launch_bounds__(256) void agg_item_kernel(
    const unsigned short* __restrict__ Whc,
    const int* __restrict__ offs_c, const int* __restrict__ srt_c,
    const float* __restrict__ W2r, const float* __restrict__ b2r,
    float* __restrict__ h2i, float* __restrict__ Y2r) {
  int t = blockIdx.x * 256 + threadIdx.x;
  int d = t >> 4, q = t & 15;
  if (d >= NI) return;

  float ac[4] = {0.f, 0.f, 0.f, 0.f};
  int c0 = offs_c[d], c1 = offs_c[d + 1];
  for (int e = c0; e < c1; ++e) {
    int s = srt_c[e];
    ushort4 v = *(const ushort4*)&Whc[(size_t)s * 64 + q * 4];
    ac[0] += bf2f(v.x); ac[1] += bf2f(v.y); ac[2] += bf2f(v.z); ac[3] += bf2f(v.w);
  }
  float rc = 1.0f / fmaxf((float)(c1 - c0), 1.0f);

  float h[4];
  #pragma unroll
  for (int i = 0; i < 4; ++i) {
    float x = ac[i] * rc;
    h[i] = x >= 0.f ? x : 0.01f * x;
  }
  *(float4*)&h2i[(size_t)d * 64 + q * 4] = make_float4(h[0], h[1], h[2], h[3]);

  float p0 = 0.f, p1 = 0.f;
  #pragma unroll
  for (int i = 0; i < 4; ++i) {
    int j = q * 4 + i;
    p0 += h[i] * W2r[j * 2 + 0]; p1 += h[i] * W2r[j * 2 + 1];
  }
  #pragma unroll
  for (int off = 1; off < 16; off <<= 1) {
    p0 += __shfl_xor(p0, off, 64);
    p1 += __shfl_xor(p1, off, 64);
  }
  if (q == 0) {
    Y2r[(size_t)d * 2 + 0] = p0 + b2r[0];
    Y2r[(size_t)d * 2 + 1] = p1 + b2r[1];
  }
}

// ---------------- layer-2 gather (tables are tiny, L2-resident) ----------------
__global__ void out_user_kernel(const float* __restrict__ Y2f, const float* __restrict__ Y2r,
                                const int* __restrict__ offs_f, const int* __restrict__ srt_f,
                                const int* __restrict__ offs_r, const int* __restrict__ srt_r,
                                float* __restrict__ out_u) {
  int d = blockIdx.x * blockDim.x + threadIdx.x;
  if (d >= NU) return;
  int f0 = offs_f[d], f1 = offs_f[d + 1];
  float a0 = 0.f, a1 = 0.f;
  for (int e = f0; e < f1; ++e) {
    int s = srt_f[e];
    a0 += Y2f[(size_t)s * 2 + 0]; a1 += Y2f[(size_t)s * 2 + 1];
  }
  float rf = 1.0f / fmaxf((float)(f1 - f0), 1.0f);
  int r0 = offs_r[d], r1 = offs_r[d + 1];
  float c0 = 0.f, c1 = 0.f;
  for (int e = r0; e < r1; ++e) {
    int s = srt_r[e];
    c0 += Y2r[(size_t)s * 2 + 0]; c1 += Y2r[(size_t)s * 2 + 1];
  }
  float rr = 1.0f / fmaxf((float)(r1 - r0), 1.0f);
  out_u[(size_t)d * 2 + 0] = a0 * rf + c0 * rr;
  out_u[(size_t)d * 2 + 1] = a1 * rf + c1 * rr;
}

__global__ void out_item_kernel(const float* __restrict__ Y2c,
                                const int* __restrict__ offs_c, const int* __restrict__ srt_c,
                                float* __restrict__ out_i) {
  int d = blockIdx.x * blockDim.x + threadIdx.x;
  if (d >= NI) return;
  int c0o = offs_c[d], c1o = offs_c[d + 1];
  float a0 = 0.f, a1 = 0.f;
  for (int e = c0o; e < c1o; ++e) {
    int s = srt_c[e];
    a0 += Y2c[(size_t)s * 2 + 0]; a1 += Y2c[(size_t)s * 2 + 1];
  }
  float rc = 1.0f / fmaxf((float)(c1o - c0o), 1.0f);
  out_i[(size_t)d * 2 + 0] = a0 * rc;
  out_i[(size_t)d * 2 + 1] = a1 * rc;
}

extern "C" void kernel_launch(void* const* d_in, const int* in_sizes, int n_in,
                              void* d_out, int out_size, void* d_ws, size_t ws_size,
                              hipStream_t stream) {
  const float* feat_user = (const float*)d_in[0];
  const float* feat_item = (const float*)d_in[1];
  const float* W1f = (const float*)d_in[2];  const float* b1f = (const float*)d_in[3];
  const float* W1c = (const float*)d_in[4];  const float* b1c = (const float*)d_in[5];
  const float* W1r = (const float*)d_in[6];  const float* b1r = (const float*)d_in[7];
  const float* W2f = (const float*)d_in[8];  const float* b2f = (const float*)d_in[9];
  const float* W2c = (const float*)d_in[10]; const float* b2c = (const float*)d_in[11];
  const float* W2r = (const float*)d_in[12]; const float* b2r = (const float*)d_in[13];
  const int* fsrc = (const int*)d_in[14];  const int* fdst = (const int*)d_in[15];
  const int* csrc = (const int*)d_in[16];  const int* cdst = (const int*)d_in[17];
  const int* rsrc = (const int*)d_in[18];  const int* rdst = (const int*)d_in[19];

  float* out = (float*)d_out;
  float* out_u = out;                 // [NU*2]
  float* out_i = out + 2 * NU;        // [NI*2]
  float* h2u  = out + 1000000;        // [NU*64]
  float* h2i  = out + 17000000;       // [NI*64]

  // ---- workspace layout ----
  unsigned short* Whf = (unsigned short*)d_ws;        // 16M bf16 = 32 MB
  unsigned short* Whc = Whf + 16000000;
  unsigned short* Whr = Whc + 16000000;
  int* ibase = (int*)(Whr + 16000000);                // 96 MB offset
  const size_t ESTRIDE = 1251008;                     // ints per etype block
  int* offs_f = ibase + 0 * ESTRIDE;
  int* cur_f  = offs_f + 250304;
  int* srt_f  = cur_f + 250304;
  int* deg_f  = srt_f + 500096;
  int* offs_c = ibase + 1 * ESTRIDE;
  int* cur_c  = offs_c + 250304;
  int* srt_c  = cur_c + 250304;
  int* deg_c  = srt_c + 500096;
  int* offs_r = ibase + 2 * ESTRIDE;
  int* cur_r  = offs_r + 250304;
  int* srt_r  = cur_r + 250304;
  int* deg_r  = srt_r + 500096;
  int* bsum   = ibase + 3 * ESTRIDE;                  // 256 ints
  float* Y2f  = (float*)(bsum + 256);                 // 500K floats each
  float* Y2c  = Y2f + 500000;
  float* Y2r  = Y2c + 500000;

  size_t need = 96000000ull + (3ull * ESTRIDE + 256ull + 1500000ull) * 4ull;
  if (ws_size < need) {
    fprintf(stderr, "kernel_launch: ws too small (%zu < %zu)\n", ws_size, need);
    return;
  }

  hipMemsetAsync(deg_f, 0, (size_t)ND * 4, stream);
  hipMemsetAsync(deg_c, 0, (size_t)ND * 4, stream);
  hipMemsetAsync(deg_r, 0, (size_t)ND * 4, stream);

  const int eb = (NE + 255) / 256;

  // layer-1 GEMMs (independent of CSR build)
  gemm_kernel<true><<<(NU + 63) / 64, 256, 0, stream>>>(feat_user, NU, W1f, b1f, W1c, b1c, Whf, Whc);
  gemm_kernel<false><<<(NI + 63) / 64, 256, 0, stream>>>(feat_item, NI, W1r, b1r, nullptr, nullptr, Whr, nullptr);

  // CSR builds (counting sort by dst)
  hist_kernel<<<eb, 256, 0, stream>>>(fdst, deg_f);
  scan1_kernel<<<NB_SCAN, 256, 0, stream>>>(deg_f, bsum);
  scan2_kernel<<<1, 256, 0, stream>>>(bsum);
  scan3_kernel<<<NB_SCAN, 256, 0, stream>>>(deg_f, bsum, offs_f, cur_f);
  bucket_kernel<<<eb, 256, 0, stream>>>(fsrc, fdst, cur_f, srt_f);

  hist_kernel<<<eb, 256, 0, stream>>>(cdst, deg_c);
  scan1_kernel<<<NB_SCAN, 256, 0, stream>>>(deg_c, bsum);
  scan2_kernel<<<1, 256, 0, stream>>>(bsum);
  scan3_kernel<<<NB_SCAN, 256, 0, stream>>>(deg_c, bsum, offs_c, cur_c);
  bucket_kernel<<<eb, 256, 0, stream>>>(csrc, cdst, cur_c, srt_c);

  hist_kernel<<<eb, 256, 0, stream>>>(rdst, deg_r);
  scan1_kernel<<<NB_SCAN, 256, 0, stream>>>(deg_r, bsum);
  scan2_kernel<<<1, 256, 0, stream>>>(bsum);
  scan3_kernel<<<NB_SCAN, 256, 0, stream>>>(deg_r, bsum, offs_r, cur_r);
  bucket_kernel<<<eb, 256, 0, stream>>>(rsrc, rdst, cur_r, srt_r);

  // layer-1 aggregation + fused leaky + fused layer-2 transform
  const int ab = (NU * 16 + 255) / 256;  // 15625
  agg_user_kernel<<<ab, 256, 0, stream>>>(Whf, Whr, offs_f, srt_f, offs_r, srt_r,
                                          W2f, b2f, W2c, b2c, h2u, Y2f, Y2c);
  agg_item_kernel<<<ab, 256, 0, stream>>>(Whc, offs_c, srt_c, W2r, b2r, h2i, Y2r);

  // layer-2 aggregation from L2-resident tables
  const int nb = (NU + 255) / 256;
  out_user_kernel<<<nb, 256, 0, stream>>>(Y2f, Y2r, offs_f, srt_f, offs_r, srt_r, out_u);
  out_item_kernel<<<nb, 256, 0, stream>>>(Y2c, offs_c, srt_c, out_i);
}

// Round 3
// 417.991 us; speedup vs baseline: 4.4647x; 1.3187x over previous
//
#include <hip/hip_runtime.h>
#include <cstdio>

#define NU 250000
#define NI 250000
#define NE 500000
#define ND 250000            // all three dst domains are 250K
#define NB_SCAN 245          // ceil(ND / 1024)

typedef __attribute__((ext_vector_type(8))) short short8v;   // 8 bf16 (4 VGPR)
typedef __attribute__((ext_vector_type(4))) float float4v;   // MFMA acc

// ---- bf16 helpers (bit-level, round-to-nearest-even) ----
__device__ inline unsigned short f2bf(float x) {
  unsigned int b = __float_as_uint(x);
  unsigned int r = (b + 0x7FFFu + ((b >> 16) & 1u)) >> 16;
  return (unsigned short)r;
}
__device__ inline float bf2f(unsigned short u) {
  return __uint_as_float(((unsigned int)u) << 16);
}

// ---------------- CSR build: histogram -> scan -> bucket fill ----------------
__global__ void hist_kernel(const int* __restrict__ dst, int* __restrict__ deg) {
  int i = blockIdx.x * blockDim.x + threadIdx.x;
  if (i < NE) atomicAdd(&deg[dst[i]], 1);
}

__global__ void scan1_kernel(const int* __restrict__ deg, int* __restrict__ bsum) {
  __shared__ int s[256];
  int b = blockIdx.x, t = threadIdx.x;
  int base = b * 1024 + t * 4;
  int v = 0;
  #pragma unroll
  for (int i = 0; i < 4; ++i) if (base + i < ND) v += deg[base + i];
  s[t] = v; __syncthreads();
  for (int off = 128; off > 0; off >>= 1) { if (t < off) s[t] += s[t + off]; __syncthreads(); }
  if (t == 0) bsum[b] = s[0];
}

__global__ void scan2_kernel(int* __restrict__ bsum) {
  __shared__ int s[256];
  int t = threadIdx.x;
  s[t] = (t < NB_SCAN) ? bsum[t] : 0;
  __syncthreads();
  for (int off = 1; off < 256; off <<= 1) {
    int x = (t >= off) ? s[t - off] : 0;
    __syncthreads();
    s[t] += x;
    __syncthreads();
  }
  if (t < NB_SCAN) bsum[t] = (t == 0) ? 0 : s[t - 1];
}

__global__ void scan3_kernel(const int* __restrict__ deg, const int* __restrict__ bsum,
                             int* __restrict__ offs, int* __restrict__ cursor) {
  __shared__ int s[256];
  int b = blockIdx.x, t = threadIdx.x;
  int base = b * 1024 + t * 4;
  int v[4]; int sum = 0;
  #pragma unroll
  for (int i = 0; i < 4; ++i) { v[i] = (base + i < ND) ? deg[base + i] : 0; sum += v[i]; }
  s[t] = sum; __syncthreads();
  for (int off = 1; off < 256; off <<= 1) {
    int x = (t >= off) ? s[t - off] : 0;
    __syncthreads();
    s[t] += x;
    __syncthreads();
  }
  int run = bsum[b] + s[t] - sum;
  #pragma unroll
  for (int i = 0; i < 4; ++i) {
    if (base + i < ND) { offs[base + i] = run; cursor[base + i] = run; run += v[i]; }
  }
  if (b == 0 && t == 0) offs[ND] = NE;
}

__global__ void bucket_kernel(const int* __restrict__ src, const int* __restrict__ dst,
                              int* __restrict__ cursor, int* __restrict__ sorted) {
  int e = blockIdx.x * blockDim.x + threadIdx.x;
  if (e < NE) {
    int pos = atomicAdd(&cursor[dst[e]], 1);
    sorted[pos] = src[e];
  }
}

// ---------------- layer-1 MFMA GEMM: Y = X[n,128] @ W[128,64] + b -> bf16 ----------------
// Swapped orientation: A-operand = W^T (outcols as M, from LDS),
// B-operand = X^T (nodes as N, from global w/ fp32->bf16 convert).
// D: col(lane&15) = node, row((lane>>4)*4+r) = outcol -> ushort4 stores.
template <bool TWO>
__global__ __launch_bounds__(256) void gemm_kernel(
    const float* __restrict__ X, int n,
    const float* __restrict__ Wa, const float* __restrict__ ba,
    const float* __restrict__ Wb, const float* __restrict__ bb,
    unsigned short* __restrict__ Ya, unsigned short* __restrict__ Yb) {
  __shared__ short sW[(TWO ? 2 : 1) * 8192];  // [et][c(4)][jm(4)][lane(64)][8] bf16 frags
  const int tid = threadIdx.x;
  const int lane = tid & 63;
  const int wave = tid >> 6;
  const int n0 = blockIdx.x * 64;

  // stage W fragments: gid = c*256 + jm*64 + lane, elem i -> W[(c*32+(lane>>4)*8+i)*64 + jm*16+(lane&15)]
  const int ngroups = (TWO ? 2048 : 1024);
  for (int g = tid; g < ngroups; g += 256) {
    int et = g >> 10;
    int gid = g & 1023;
    int gl = gid & 63;
    int jm = (gid >> 6) & 3;
    int c = gid >> 8;
    int kb = c * 32 + (gl >> 4) * 8;
    int col = jm * 16 + (gl & 15);
    const float* Wsrc = (TWO && et) ? Wb : Wa;
    short8v u;
    #pragma unroll
    for (int i = 0; i < 8; ++i) u[i] = (short)f2bf(Wsrc[(kb + i) * 64 + col]);
    ((short8v*)sW)[g] = u;
  }
  __syncthreads();

  int node = n0 + wave * 16 + (lane & 15);
  int rowc = node < n ? node : (n - 1);           // clamped for loads
  const float* xrow = X + (size_t)rowc * 128 + (lane >> 4) * 8;

  float4v accA[4] = {};
  float4v accB[4] = {};

  #pragma unroll
  for (int c = 0; c < 4; ++c) {
    float4 f0 = *(const float4*)(xrow + c * 32);
    float4 f1 = *(const float4*)(xrow + c * 32 + 4);
    short8v bfr;
    bfr[0] = (short)f2bf(f0.x); bfr[1] = (short)f2bf(f0.y);
    bfr[2] = (short)f2bf(f0.z); bfr[3] = (short)f2bf(f0.w);
    bfr[4] = (short)f2bf(f1.x); bfr[5] = (short)f2bf(f1.y);
    bfr[6] = (short)f2bf(f1.z); bfr[7] = (short)f2bf(f1.w);
    #pragma unroll
    for (int jm = 0; jm < 4; ++jm) {
      short8v a = ((short8v*)sW)[c * 256 + jm * 64 + lane];
      accA[jm] = __builtin_amdgcn_mfma_f32_16x16x32_bf16(a, bfr, accA[jm], 0, 0, 0);
      if constexpr (TWO) {
        short8v a2 = ((short8v*)sW)[1024 + c * 256 + jm * 64 + lane];
        accB[jm] = __builtin_amdgcn_mfma_f32_16x16x32_bf16(a2, bfr, accB[jm], 0, 0, 0);
      }
    }
  }

  if (node < n) {
    const int cb = (lane >> 4) * 4;   // output col base within 16-tile
    #pragma unroll
    for (int jm = 0; jm < 4; ++jm) {
      float4 bias = *(const float4*)&ba[jm * 16 + cb];
      ushort4 o;
      o.x = f2bf(accA[jm][0] + bias.x);
      o.y = f2bf(accA[jm][1] + bias.y);
      o.z = f2bf(accA[jm][2] + bias.z);
      o.w = f2bf(accA[jm][3] + bias.w);
      *(ushort4*)&Ya[(size_t)node * 64 + jm * 16 + cb] = o;
      if constexpr (TWO) {
        float4 bias2 = *(const float4*)&bb[jm * 16 + cb];
        ushort4 o2;
        o2.x = f2bf(accB[jm][0] + bias2.x);
        o2.y = f2bf(accB[jm][1] + bias2.y);
        o2.z = f2bf(accB[jm][2] + bias2.z);
        o2.w = f2bf(accB[jm][3] + bias2.w);
        *(ushort4*)&Yb[(size_t)node * 64 + jm * 16 + cb] = o2;
      }
    }
  }
}

// ---------------- layer-1 gather-aggregate for users (follows + rev), fused leaky + layer-2 GEMM ----------------
__global__ __launch_bounds__(256) void agg_user_kernel(
    const unsigned short* __restrict__ Whf, const unsigned short* __restrict__ Whr,
    const int* __restrict__ offs_f, const int* __restrict__ srt_f,
    const int* __restrict__ offs_r, const int* __restrict__ srt_r,
    const float* __restrict__ W2f, const float* __restrict__ b2f,
    const float* __restrict__ W2c, const float* __restrict__ b2c,
    float* __restrict__ h2u, float* __restrict__ Y2f, float* __restrict__ Y2c) {
  int t = blockIdx.x * 256 + threadIdx.x;
  int d = t >> 4, q = t & 15;
  if (d >= NU) return;

  float af[4] = {0.f, 0.f, 0.f, 0.f};
  int f0 = offs_f[d], f1 = offs_f[d + 1];
  for (int e = f0; e < f1; ++e) {
    int s = srt_f[e];
    ushort4 v = *(const ushort4*)&Whf[(size_t)s * 64 + q * 4];
    af[0] += bf2f(v.x); af[1] += bf2f(v.y); af[2] += bf2f(v.z); af[3] += bf2f(v.w);
  }
  float rf = 1.0f / fmaxf((float)(f1 - f0), 1.0f);

  float ar[4] = {0.f, 0.f, 0.f, 0.f};
  int r0 = offs_r[d], r1 = offs_r[d + 1];
  for (int e = r0; e < r1; ++e) {
    int s = srt_r[e];
    ushort4 v = *(const ushort4*)&Whr[(size_t)s * 64 + q * 4];
    ar[0] += bf2f(v.x); ar[1] += bf2f(v.y); ar[2] += bf2f(v.z); ar[3] += bf2f(v.w);
  }
  float rr = 1.0f / fmaxf((float)(r1 - r0), 1.0f);

  float h[4];
  #pragma unroll
  for (int i = 0; i < 4; ++i) {
    float x = af[i] * rf + ar[i] * rr;
    h[i] = x >= 0.f ? x : 0.01f * x;
  }
  *(float4*)&h2u[(size_t)d * 64 + q * 4] = make_float4(h[0], h[1], h[2], h[3]);

  float pf0 = 0.f, pf1 = 0.f, pc0 = 0.f, pc1 = 0.f;
  #pragma unroll
  for (int i = 0; i < 4; ++i) {
    int j = q * 4 + i;
    pf0 += h[i] * W2f[j * 2 + 0]; pf1 += h[i] * W2f[j * 2 + 1];
    pc0 += h[i] * W2c[j * 2 + 0]; pc1 += h[i] * W2c[j * 2 + 1];
  }
  #pragma unroll
  for (int off = 1; off < 16; off <<= 1) {
    pf0 += __shfl_xor(pf0, off, 64);
    pf1 += __shfl_xor(pf1, off, 64);
    pc0 += __shfl_xor(pc0, off, 64);
    pc1 += __shfl_xor(pc1, off, 64);
  }
  if (q == 0) {
    Y2f[(size_t)d * 2 + 0] = pf0 + b2f[0];
    Y2f[(size_t)d * 2 + 1] = pf1 + b2f[1];
    Y2c[(size_t)d * 2 + 0] = pc0 + b2c[0];
    Y2c[(size_t)d * 2 + 1] = pc1 + b2c[1];
  }
}

// ---------------- layer-1 gather-aggregate for items (clicks), fused leaky + layer-2 GEMM (rev) ----------------
__global__ __launch_bounds__(256) void agg_item_kernel(
    const unsigned short* __restrict__ Whc,
    const int* __restrict__ offs_c, const int* __restrict__ srt_c,
    const float* __restrict__ W2r, const float* __restrict__ b2r,
    float* __restrict__ h2i, float* __restrict__ Y2r) {
  int t = blockIdx.x * 256 + threadIdx.x;
  int d = t >> 4, q = t & 15;
  if (d >= NI) return;

  float ac[4] = {0.f, 0.f, 0.f, 0.f};
  int c0 = offs_c[d], c1 = offs_c[d + 1];
  for (int e = c0; e < c1; ++e) {
    int s = srt_c[e];
    ushort4 v = *(const ushort4*)&Whc[(size_t)s * 64 + q * 4];
    ac[0] += bf2f(v.x); ac[1] += bf2f(v.y); ac[2] += bf2f(v.z); ac[3] += bf2f(v.w);
  }
  float rc = 1.0f / fmaxf((float)(c1 - c0), 1.0f);

  float h[4];
  #pragma unroll
  for (int i = 0; i < 4; ++i) {
    float x = ac[i] * rc;
    h[i] = x >= 0.f ? x : 0.01f * x;
  }
  *(float4*)&h2i[(size_t)d * 64 + q * 4] = make_float4(h[0], h[1], h[2], h[3]);

  float p0 = 0.f, p1 = 0.f;
  #pragma unroll
  for (int i = 0; i < 4; ++i) {
    int j = q * 4 + i;
    p0 += h[i] * W2r[j * 2 + 0]; p1 += h[i] * W2r[j * 2 + 1];
  }
  #pragma unroll
  for (int off = 1; off < 16; off <<= 1) {
    p0 += __shfl_xor(p0, off, 64);
    p1 += __shfl_xor(p1, off, 64);
  }
  if (q == 0) {
    Y2r[(size_t)d * 2 + 0] = p0 + b2r[0];
    Y2r[(size_t)d * 2 + 1] = p1 + b2r[1];
  }
}

// ---------------- layer-2 gather (tables are tiny, L2-resident) ----------------
__global__ void out_user_kernel(const float* __restrict__ Y2f, const float* __restrict__ Y2r,
                                const int* __restrict__ offs_f, const int* __restrict__ srt_f,
                                const int* __restrict__ offs_r, const int* __restrict__ srt_r,
                                float* __restrict__ out_u) {
  int d = blockIdx.x * blockDim.x + threadIdx.x;
  if (d >= NU) return;
  int f0 = offs_f[d], f1 = offs_f[d + 1];
  float a0 = 0.f, a1 = 0.f;
  for (int e = f0; e < f1; ++e) {
    int s = srt_f[e];
    a0 += Y2f[(size_t)s * 2 + 0]; a1 += Y2f[(size_t)s * 2 + 1];
  }
  float rf = 1.0f / fmaxf((float)(f1 - f0), 1.0f);
  int r0 = offs_r[d], r1 = offs_r[d + 1];
  float c0 = 0.f, c1 = 0.f;
  for (int e = r0; e < r1; ++e) {
    int s = srt_r[e];
    c0 += Y2r[(size_t)s * 2 + 0]; c1 += Y2r[(size_t)s * 2 + 1];
  }
  float rr = 1.0f / fmaxf((float)(r1 - r0), 1.0f);
  out_u[(size_t)d * 2 + 0] = a0 * rf + c0 * rr;
  out_u[(size_t)d * 2 + 1] = a1 * rf + c1 * rr;
}

__global__ void out_item_kernel(const float* __restrict__ Y2c,
                                const int* __restrict__ offs_c, const int* __restrict__ srt_c,
                                float* __restrict__ out_i) {
  int d = blockIdx.x * blockDim.x + threadIdx.x;
  if (d >= NI) return;
  int c0o = offs_c[d], c1o = offs_c[d + 1];
  float a0 = 0.f, a1 = 0.f;
  for (int e = c0o; e < c1o; ++e) {
    int s = srt_c[e];
    a0 += Y2c[(size_t)s * 2 + 0]; a1 += Y2c[(size_t)s * 2 + 1];
  }
  float rc = 1.0f / fmaxf((float)(c1o - c0o), 1.0f);
  out_i[(size_t)d * 2 + 0] = a0 * rc;
  out_i[(size_t)d * 2 + 1] = a1 * rc;
}

extern "C" void kernel_launch(void* const* d_in, const int* in_sizes, int n_in,
                              void* d_out, int out_size, void* d_ws, size_t ws_size,
                              hipStream_t stream) {
  const float* feat_user = (const float*)d_in[0];
  const float* feat_item = (const float*)d_in[1];
  const float* W1f = (const float*)d_in[2];  const float* b1f = (const float*)d_in[3];
  const float* W1c = (const float*)d_in[4];  const float* b1c = (const float*)d_in[5];
  const float* W1r = (const float*)d_in[6];  const float* b1r = (const float*)d_in[7];
  const float* W2f = (const float*)d_in[8];  const float* b2f = (const float*)d_in[9];
  const float* W2c = (const float*)d_in[10]; const float* b2c = (const float*)d_in[11];
  const float* W2r = (const float*)d_in[12]; const float* b2r = (const float*)d_in[13];
  const int* fsrc = (const int*)d_in[14];  const int* fdst = (const int*)d_in[15];
  const int* csrc = (const int*)d_in[16];  const int* cdst = (const int*)d_in[17];
  const int* rsrc = (const int*)d_in[18];  const int* rdst = (const int*)d_in[19];

  float* out = (float*)d_out;
  float* out_u = out;                 // [NU*2]
  float* out_i = out + 2 * NU;        // [NI*2]
  float* h2u  = out + 1000000;        // [NU*64]
  float* h2i  = out + 17000000;       // [NI*64]

  // ---- workspace layout ----
  unsigned short* Whf = (unsigned short*)d_ws;        // 16M bf16 = 32 MB
  unsigned short* Whc = Whf + 16000000;
  unsigned short* Whr = Whc + 16000000;
  int* ibase = (int*)(Whr + 16000000);                // 96 MB offset
  const size_t ESTRIDE = 1251008;
  int* offs_f = ibase + 0 * ESTRIDE;
  int* cur_f  = offs_f + 250304;
  int* srt_f  = cur_f + 250304;
  int* deg_f  = srt_f + 500096;
  int* offs_c = ibase + 1 * ESTRIDE;
  int* cur_c  = offs_c + 250304;
  int* srt_c  = cur_c + 250304;
  int* deg_c  = srt_c + 500096;
  int* offs_r = ibase + 2 * ESTRIDE;
  int* cur_r  = offs_r + 250304;
  int* srt_r  = cur_r + 250304;
  int* deg_r  = srt_r + 500096;
  int* bsum   = ibase + 3 * ESTRIDE;
  float* Y2f  = (float*)(bsum + 256);
  float* Y2c  = Y2f + 500000;
  float* Y2r  = Y2c + 500000;

  size_t need = 96000000ull + (3ull * ESTRIDE + 256ull + 1500000ull) * 4ull;
  if (ws_size < need) {
    fprintf(stderr, "kernel_launch: ws too small (%zu < %zu)\n", ws_size, need);
    return;
  }

  hipMemsetAsync(deg_f, 0, (size_t)ND * 4, stream);
  hipMemsetAsync(deg_c, 0, (size_t)ND * 4, stream);
  hipMemsetAsync(deg_r, 0, (size_t)ND * 4, stream);

  const int eb = (NE + 255) / 256;

  // layer-1 GEMMs (MFMA bf16)
  gemm_kernel<true><<<(NU + 63) / 64, 256, 0, stream>>>(feat_user, NU, W1f, b1f, W1c, b1c, Whf, Whc);
  gemm_kernel<false><<<(NI + 63) / 64, 256, 0, stream>>>(feat_item, NI, W1r, b1r, nullptr, nullptr, Whr, nullptr);

  // CSR builds (counting sort by dst)
  hist_kernel<<<eb, 256, 0, stream>>>(fdst, deg_f);
  scan1_kernel<<<NB_SCAN, 256, 0, stream>>>(deg_f, bsum);
  scan2_kernel<<<1, 256, 0, stream>>>(bsum);
  scan3_kernel<<<NB_SCAN, 256, 0, stream>>>(deg_f, bsum, offs_f, cur_f);
  bucket_kernel<<<eb, 256, 0, stream>>>(fsrc, fdst, cur_f, srt_f);

  hist_kernel<<<eb, 256, 0, stream>>>(cdst, deg_c);
  scan1_kernel<<<NB_SCAN, 256, 0, stream>>>(deg_c, bsum);
  scan2_kernel<<<1, 256, 0, stream>>>(bsum);
  scan3_kernel<<<NB_SCAN, 256, 0, stream>>>(deg_c, bsum, offs_c, cur_c);
  bucket_kernel<<<eb, 256, 0, stream>>>(csrc, cdst, cur_c, srt_c);

  hist_kernel<<<eb, 256, 0, stream>>>(rdst, deg_r);
  scan1_kernel<<<NB_SCAN, 256, 0, stream>>>(deg_r, bsum);
  scan2_kernel<<<1, 256, 0, stream>>>(bsum);
  scan3_kernel<<<NB_SCAN, 256, 0, stream>>>(deg_r, bsum, offs_r, cur_r);
  bucket_kernel<<<eb, 256, 0, stream>>>(rsrc, rdst, cur_r, srt_r);

  // layer-1 aggregation + fused leaky + fused layer-2 transform
  const int ab = (NU * 16 + 255) / 256;
  agg_user_kernel<<<ab, 256, 0, stream>>>(Whf, Whr, offs_f, srt_f, offs_r, srt_r,
                                          W2f, b2f, W2c, b2c, h2u, Y2f, Y2c);
  agg_item_kernel<<<ab, 256, 0, stream>>>(Whc, offs_c, srt_c, W2r, b2r, h2i, Y2r);

  // layer-2 aggregation from L2-resident tables
  const int nb = (NU + 255) / 256;
  out_user_kernel<<<nb, 256, 0, stream>>>(Y2f, Y2r, offs_f, srt_f, offs_r, srt_r, out_u);
  out_item_kernel<<<nb, 256, 0, stream>>>(Y2c, offs_c, srt_c, out_i);
}